// Round 12
// baseline (2934.143 us; speedup 1.0000x reference)
//
#include <hip/hip_runtime.h>
#include <hip/hip_bf16.h>
#include <cstdint>

#define N_NODES 50000
#define N_EDGES 800000
#define DIM     128
#define NLAYERS 4

#define SCAN_BLK 256
#define NB ((N_NODES + SCAN_BLK - 1) / SCAN_BLK)   // 196 scan blocks

// ---------------- CSR build (single-pass) ----------------

__global__ __launch_bounds__(256) void zero_kernel(int* __restrict__ p, int n) {
    int i = blockIdx.x * blockDim.x + threadIdx.x;
    if (i < n) p[i] = 0;
}

__global__ __launch_bounds__(256) void count_kernel(const int* __restrict__ key,
                                                    int* __restrict__ cnt) {
    int e = blockIdx.x * blockDim.x + threadIdx.x;
    if (e < N_EDGES) atomicAdd(&cnt[key[e]], 1);
}

__global__ __launch_bounds__(SCAN_BLK) void scanA(const int* __restrict__ cnt,
                                                  int* __restrict__ off,
                                                  int* __restrict__ bsum) {
    __shared__ int s[SCAN_BLK];
    const int t = threadIdx.x;
    const int i = blockIdx.x * SCAN_BLK + t;
    int v = (i < N_NODES) ? cnt[i] : 0;
    s[t] = v;
    __syncthreads();
    for (int d = 1; d < SCAN_BLK; d <<= 1) {
        int add = (t >= d) ? s[t - d] : 0;
        __syncthreads();
        s[t] += add;
        __syncthreads();
    }
    if (i < N_NODES) off[i] = s[t] - v;
    if (t == SCAN_BLK - 1) bsum[blockIdx.x] = s[t];
}

__global__ __launch_bounds__(SCAN_BLK) void scanB(int* __restrict__ bsum) {
    __shared__ int s[SCAN_BLK];
    const int t = threadIdx.x;
    int v = (t < NB) ? bsum[t] : 0;
    s[t] = v;
    __syncthreads();
    for (int d = 1; d < SCAN_BLK; d <<= 1) {
        int add = (t >= d) ? s[t - d] : 0;
        __syncthreads();
        s[t] += add;
        __syncthreads();
    }
    if (t < NB) bsum[t] = s[t] - v;
}

__global__ __launch_bounds__(SCAN_BLK) void scanC(int* __restrict__ off,
                                                  const int* __restrict__ bsum,
                                                  int* __restrict__ cur) {
    const int i = blockIdx.x * SCAN_BLK + threadIdx.x;
    if (i < N_NODES) {
        int o = off[i] + bsum[blockIdx.x];
        off[i] = o;
        cur[i] = o;
    }
    if (i == 0) off[N_NODES] = N_EDGES;
}

__global__ __launch_bounds__(256) void scatter_kernel(const int* __restrict__ src,
                                                      const int* __restrict__ dst,
                                                      int* __restrict__ cur,
                                                      int* __restrict__ csr) {
    int e = blockIdx.x * blockDim.x + threadIdx.x;
    if (e < N_EDGES) {
        int d = dst[e];
        int pos = atomicAdd(&cur[d], 1);
        csr[pos] = src[e];
    }
}

// ---------------- bf16 helpers ----------------

static __device__ __forceinline__ float bf2f(unsigned short u) {
    unsigned v = (unsigned)u << 16;
    float f;
    __builtin_memcpy(&f, &v, 4);
    return f;
}
static __device__ __forceinline__ unsigned short f2bf(float f) {
    __hip_bfloat16 h = __float2bfloat16(f);   // RNE
    unsigned short u;
    __builtin_memcpy(&u, &h, 2);
    return u;
}

__global__ __launch_bounds__(256) void conv_kernel(const float* __restrict__ x,
                                                   unsigned short* __restrict__ xh) {
    int i = blockIdx.x * blockDim.x + threadIdx.x;   // float4 index
    const int n4 = N_NODES * DIM / 4;
    if (i < n4) {
        float4 v = reinterpret_cast<const float4*>(x)[i];
        ushort4 h;
        h.x = f2bf(v.x); h.y = f2bf(v.y); h.z = f2bf(v.z); h.w = f2bf(v.w);
        reinterpret_cast<ushort4*>(xh)[i] = h;
    }
}

// ---------------- agg kernel: node-per-group deep-ILP gather ----------------
// (unchanged from R11: ~36 µs/layer)

__global__ __launch_bounds__(256) void agg_kernel(
    const float* __restrict__ xin,
    const unsigned short* __restrict__ xh,
    const int* __restrict__ off,
    const int* __restrict__ csr,
    float* __restrict__ agg)
{
    const int tid  = threadIdx.x;
    const int c    = tid & 31;
    const int node = blockIdx.x * 8 + (tid >> 5);
    if (node >= N_NODES) return;

    const float4*  xin4 = reinterpret_cast<const float4*>(xin);
    const ushort4* xh4  = reinterpret_cast<const ushort4*>(xh);

    const int k0 = off[node], k1 = off[node + 1];
    float4 a = xin4[node * 32 + c];

    for (int kb = k0; kb < k1; kb += 32) {
        const int m = min(32, k1 - kb);
        int idxv = (c < m) ? csr[kb + c] : 0;
        ushort4 v[16], v2[16];
        #pragma unroll
        for (int j = 0; j < 16; ++j) {
            int id = __shfl(idxv, j, 32);
            if (j < m) v[j] = xh4[id * 32 + c];
        }
        #pragma unroll
        for (int j = 0; j < 16; ++j) {
            int id = __shfl(idxv, j + 16, 32);
            if (j + 16 < m) v2[j] = xh4[id * 32 + c];
        }
        #pragma unroll
        for (int j = 0; j < 16; ++j) {
            if (j < m) {
                a.x += bf2f(v[j].x); a.y += bf2f(v[j].y);
                a.z += bf2f(v[j].z); a.w += bf2f(v[j].w);
            }
        }
        #pragma unroll
        for (int j = 0; j < 16; ++j) {
            if (j + 16 < m) {
                a.x += bf2f(v2[j].x); a.y += bf2f(v2[j].y);
                a.z += bf2f(v2[j].z); a.w += bf2f(v2[j].w);
            }
        }
    }
    reinterpret_cast<float4*>(agg)[node * 32 + c] = a;
}

// ---------------- mlp kernel: GEMM1+ReLU -> GEMM2, W staged in LDS ----------
// W is consumed in 16 KB chunks (32 K-rows x 128 cols) staged in sW; the NEXT
// chunk's global loads are issued into registers BEFORE computing the current
// chunk, hiding L2 latency under ~1000cy of FMAs (R11 post-mortem: per-thread
// W loads from global left VALUBusy at 33%).

#define RT 32
#define LDW 132    // padded row stride for sA (floats)

__global__ __launch_bounds__(256) void mlp_kernel(
    const float* __restrict__ agg,
    const float* __restrict__ W1, const float* __restrict__ b1,
    const float* __restrict__ W2, const float* __restrict__ b2,
    float* __restrict__ xout,
    unsigned short* __restrict__ xhout)
{
    __shared__ float sA[RT][LDW];
    __shared__ float sW[32 * DIM];          // one 16 KB W chunk
    const int tid  = threadIdx.x;
    const int base = blockIdx.x * RT;

    // ---- stage agg rows into sA (coalesced float4) ----
    {
        const float4* agg4 = reinterpret_cast<const float4*>(agg);
        for (int i = tid; i < RT * 32; i += 256) {
            const int r = i >> 5, cc = i & 31;
            if (base + r < N_NODES) {
                *reinterpret_cast<float4*>(&sA[r][cc * 4]) = agg4[(base + r) * 32 + cc];
            }
        }
    }

    const int tc = tid & 31;
    const int tr = tid >> 5;
    float4* sW4 = reinterpret_cast<float4*>(sW);

    // ---- GEMM1: acc = relu(sA @ W1 + b1) ----
    float acc[4][4] = {};
    {
        const float4* Wg = reinterpret_cast<const float4*>(W1);
        float4 pre[4];
        #pragma unroll
        for (int q = 0; q < 4; ++q) pre[q] = Wg[q * 256 + tid];   // chunk 0
        #pragma unroll
        for (int kb = 0; kb < 4; ++kb) {
            __syncthreads();               // sW free (and sA ready on kb==0)
            #pragma unroll
            for (int q = 0; q < 4; ++q) sW4[q * 256 + tid] = pre[q];
            __syncthreads();               // chunk visible
            if (kb < 3) {
                #pragma unroll
                for (int q = 0; q < 4; ++q) pre[q] = Wg[(kb + 1) * 1024 + q * 256 + tid];
            }
            #pragma unroll
            for (int k4 = 0; k4 < 8; ++k4) {
                float4 w[4];
                #pragma unroll
                for (int j = 0; j < 4; ++j) w[j] = sW4[(k4 * 4 + j) * 32 + tc];
                #pragma unroll
                for (int i = 0; i < 4; ++i) {
                    const float4 a = *reinterpret_cast<const float4*>(
                        &sA[tr * 4 + i][(kb * 8 + k4) * 4]);
                    acc[i][0] += a.x * w[0].x + a.y * w[1].x + a.z * w[2].x + a.w * w[3].x;
                    acc[i][1] += a.x * w[0].y + a.y * w[1].y + a.z * w[2].y + a.w * w[3].y;
                    acc[i][2] += a.x * w[0].z + a.y * w[1].z + a.z * w[2].z + a.w * w[3].z;
                    acc[i][3] += a.x * w[0].w + a.y * w[1].w + a.z * w[2].w + a.w * w[3].w;
                }
            }
        }
        const float4 b = reinterpret_cast<const float4*>(b1)[tc];
        #pragma unroll
        for (int i = 0; i < 4; ++i) {
            acc[i][0] = fmaxf(acc[i][0] + b.x, 0.f);
            acc[i][1] = fmaxf(acc[i][1] + b.y, 0.f);
            acc[i][2] = fmaxf(acc[i][2] + b.z, 0.f);
            acc[i][3] = fmaxf(acc[i][3] + b.w, 0.f);
        }
    }
    __syncthreads();   // all reads of sA complete

    // write H back into sA (reuse)
    #pragma unroll
    for (int i = 0; i < 4; ++i) {
        float4 h;
        h.x = acc[i][0]; h.y = acc[i][1]; h.z = acc[i][2]; h.w = acc[i][3];
        *reinterpret_cast<float4*>(&sA[tr * 4 + i][tc * 4]) = h;
    }

    // ---- GEMM2: xout = sA(=H) @ W2 + b2, plus bf16 shadow ----
    {
        float acc2[4][4] = {};
        const float4* Wg = reinterpret_cast<const float4*>(W2);
        float4 pre[4];
        #pragma unroll
        for (int q = 0; q < 4; ++q) pre[q] = Wg[q * 256 + tid];   // chunk 0
        #pragma unroll
        for (int kb = 0; kb < 4; ++kb) {
            __syncthreads();               // sW free (and H-writes done on kb==0)
            #pragma unroll
            for (int q = 0; q < 4; ++q) sW4[q * 256 + tid] = pre[q];
            __syncthreads();
            if (kb < 3) {
                #pragma unroll
                for (int q = 0; q < 4; ++q) pre[q] = Wg[(kb + 1) * 1024 + q * 256 + tid];
            }
            #pragma unroll
            for (int k4 = 0; k4 < 8; ++k4) {
                float4 w[4];
                #pragma unroll
                for (int j = 0; j < 4; ++j) w[j] = sW4[(k4 * 4 + j) * 32 + tc];
                #pragma unroll
                for (int i = 0; i < 4; ++i) {
                    const float4 a = *reinterpret_cast<const float4*>(
                        &sA[tr * 4 + i][(kb * 8 + k4) * 4]);
                    acc2[i][0] += a.x * w[0].x + a.y * w[1].x + a.z * w[2].x + a.w * w[3].x;
                    acc2[i][1] += a.x * w[0].y + a.y * w[1].y + a.z * w[2].y + a.w * w[3].y;
                    acc2[i][2] += a.x * w[0].z + a.y * w[1].z + a.z * w[2].z + a.w * w[3].z;
                    acc2[i][3] += a.x * w[0].w + a.y * w[1].w + a.z * w[2].w + a.w * w[3].w;
                }
            }
        }
        const float4 b = reinterpret_cast<const float4*>(b2)[tc];
        #pragma unroll
        for (int i = 0; i < 4; ++i) {
            const int node = base + tr * 4 + i;
            if (node < N_NODES) {
                float4 o;
                o.x = acc2[i][0] + b.x;
                o.y = acc2[i][1] + b.y;
                o.z = acc2[i][2] + b.z;
                o.w = acc2[i][3] + b.w;
                reinterpret_cast<float4*>(xout + node * DIM)[tc] = o;
                ushort4 h;
                h.x = f2bf(o.x); h.y = f2bf(o.y); h.z = f2bf(o.z); h.w = f2bf(o.w);
                reinterpret_cast<ushort4*>(xhout + node * DIM)[tc] = h;
            }
        }
    }
}

// ---------------- launch ----------------

extern "C" void kernel_launch(void* const* d_in, const int* in_sizes, int n_in,
                              void* d_out, int out_size, void* d_ws, size_t ws_size,
                              hipStream_t stream) {
    const float* x  = (const float*)d_in[0];
    const int*   ei = (const int*)d_in[1];     // [2][N_EDGES]: src row then dst row
    // d_in[2] = batch (unused)
    const float* W1 = (const float*)d_in[3];
    const float* b1 = (const float*)d_in[4];
    const float* W2 = (const float*)d_in[5];
    const float* b2 = (const float*)d_in[6];
    float* out = (float*)d_out;

    const int* src = ei;
    const int* dst = ei + N_EDGES;

    // workspace: fp32 ping buffer, two bf16 shadows, CSR arrays (≈55 MB).
    // d_out doubles as the agg buffer G every layer (row-local, in-place-safe).
    float*          bufA = (float*)d_ws;                                    // N*DIM f32
    unsigned short* xhA  = (unsigned short*)(bufA + (size_t)N_NODES * DIM); // N*DIM u16
    unsigned short* xhB  = xhA + (size_t)N_NODES * DIM;                     // N*DIM u16
    int*   cnt  = (int*)(xhB + (size_t)N_NODES * DIM);                      // N
    int*   offs = cnt + N_NODES;                                            // N+1
    int*   cur  = offs + N_NODES + 1;                                       // N
    int*   bsum = cur + N_NODES;                                            // 256
    int*   csr  = bsum + 256;                                               // E
    float* G    = out;                                                      // agg buffer

    // --- build CSR (dst -> srcs) ---
    zero_kernel<<<NB, 256, 0, stream>>>(cnt, N_NODES);
    count_kernel<<<(N_EDGES + 255) / 256, 256, 0, stream>>>(dst, cnt);
    scanA<<<NB, SCAN_BLK, 0, stream>>>(cnt, offs, bsum);
    scanB<<<1, SCAN_BLK, 0, stream>>>(bsum);
    scanC<<<NB, SCAN_BLK, 0, stream>>>(offs, bsum, cur);
    scatter_kernel<<<(N_EDGES + 255) / 256, 256, 0, stream>>>(src, dst, cur, csr);

    // bf16 shadow of the initial x
    conv_kernel<<<(N_NODES * DIM / 4 + 255) / 256, 256, 0, stream>>>(x, xhA);

    const int nblk_agg = (N_NODES + 7) / 8;
    const int nblk_mlp = (N_NODES + RT - 1) / RT;

    // layer 0
    agg_kernel<<<nblk_agg, 256, 0, stream>>>(x, xhA, offs, csr, G);
    mlp_kernel<<<nblk_mlp, 256, 0, stream>>>(G, W1 + 0 * DIM * DIM, b1 + 0 * DIM,
                                             W2 + 0 * DIM * DIM, b2 + 0 * DIM, bufA, xhB);
    // layer 1
    agg_kernel<<<nblk_agg, 256, 0, stream>>>(bufA, xhB, offs, csr, G);
    mlp_kernel<<<nblk_mlp, 256, 0, stream>>>(G, W1 + 1 * DIM * DIM, b1 + 1 * DIM,
                                             W2 + 1 * DIM * DIM, b2 + 1 * DIM, bufA, xhA);
    // layer 2
    agg_kernel<<<nblk_agg, 256, 0, stream>>>(bufA, xhA, offs, csr, G);
    mlp_kernel<<<nblk_mlp, 256, 0, stream>>>(G, W1 + 2 * DIM * DIM, b1 + 2 * DIM,
                                             W2 + 2 * DIM * DIM, b2 + 2 * DIM, bufA, xhB);
    // layer 3 (MLP reads G==out via LDS staging before overwriting in place)
    agg_kernel<<<nblk_agg, 256, 0, stream>>>(bufA, xhB, offs, csr, G);
    mlp_kernel<<<nblk_mlp, 256, 0, stream>>>(G, W1 + 3 * DIM * DIM, b1 + 3 * DIM,
                                             W2 + 3 * DIM * DIM, b2 + 3 * DIM, out, xhA);
}